// Round 14
// baseline (289.776 us; speedup 1.0000x reference)
//
#include <hip/hip_runtime.h>
#include <hip/hip_bf16.h>
#include <hip/hip_fp16.h>

// MHAHead B=8,S=2048,E=512. R18: R17 attn re-geometried for 2 blocks/CU.
//   R17 post-mortem: fusion worked (S round-trip gone, WRITE 67->32MB) but
//   grid=256 on 256 CUs = 1 block/CU by construction -> per-tile vmcnt drain
//   fully exposed (occ 11.7%, Mfma 12.7%). The overlap that carried R11-R15
//   was co-resident blocks; R17 had none.
//   R18: q-block 64->32 rows (2 waves, 128 thr) -> grid 512 = 2 blocks/CU
//   (LDS 68KB x2 = 136KB fits). Per-wave compute byte-identical (65 MFMA per
//   kv-tile). T5 setprio(1) around MFMA cluster (pays with phase-split blocks).
//   conv_w/conv_x/proj: identical to R16/R17 (verified).

typedef unsigned short u16;
typedef unsigned long long u64;
typedef __attribute__((ext_vector_type(8))) short short8;
typedef __attribute__((ext_vector_type(8))) _Float16 half8;
typedef __attribute__((ext_vector_type(4))) float float4v;

#define S_DIM 2048
#define E_DIM 512
#define NROWS (8 * S_DIM)
#define SCALE 0.044194173824159216f

__device__ __forceinline__ float4v mfma16(short8 a, short8 b, float4v c) {
    return __builtin_amdgcn_mfma_f32_16x16x32_f16(
        __builtin_bit_cast(half8, a), __builtin_bit_cast(half8, b), c, 0, 0, 0);
}
__device__ __forceinline__ float bf2f(unsigned int u) {
    union { unsigned int i; float f; } v; v.i = u << 16; return v.f;
}
__device__ __forceinline__ u16 f2h_bits(float f) {
    union { _Float16 h; u16 u; } v; v.h = (_Float16)f; return v.u;
}
__device__ __forceinline__ float h2f(u16 u) {
    union { u16 u; _Float16 h; } v; v.u = u; return (float)v.h;
}
// tiled u16 index for element (row, col) in a [rows][K] matrix with NT=K/32 tiles
__device__ __forceinline__ size_t tidx(int row, int col, int NT) {
    const int rr = row & 127;
    const int g = 4 * rr + (((col & 31) >> 3) ^ ((rr >> 1) & 3));
    return ((size_t)((row >> 7) * NT + (col >> 5)) * 512 + g) * 8 + (col & 7);
}
__device__ __forceinline__ int detect_bf16(const void* wp) {
    const u16* w = (const u16*)wp;
    int cnt = 0;
    for (int i = 0; i < 64; ++i) {
        int e = (w[2 * i] >> 7) & 0xff;
        cnt += (e >= 100 && e <= 131) ? 1 : 0;
    }
    return cnt >= 40;
}
__device__ __forceinline__ void load8(const void* base, size_t idx, int isbf, float* f) {
    if (isbf) {
        uint4 v = *(const uint4*)((const u16*)base + idx);
        f[0] = bf2f(v.x & 0xffffu); f[1] = bf2f(v.x >> 16);
        f[2] = bf2f(v.y & 0xffffu); f[3] = bf2f(v.y >> 16);
        f[4] = bf2f(v.z & 0xffffu); f[5] = bf2f(v.z >> 16);
        f[6] = bf2f(v.w & 0xffffu); f[7] = bf2f(v.w >> 16);
    } else {
        const float* p = (const float*)base + idx;
        float4 a = *(const float4*)p;
        float4 b = *(const float4*)(p + 4);
        f[0] = a.x; f[1] = a.y; f[2] = a.z; f[3] = a.w;
        f[4] = b.x; f[5] = b.y; f[6] = b.z; f[7] = b.w;
    }
}
__device__ __forceinline__ float load1(const void* base, size_t idx, int isbf) {
    return isbf ? bf2f(((const u16*)base)[idx]) : ((const float*)base)[idx];
}

// async 16B global -> LDS (per-lane src, wave-uniform LDS base + lane*16)
__device__ __forceinline__ void gld16(const u16* g, u16* l) {
    __builtin_amdgcn_global_load_lds(
        (const __attribute__((address_space(1))) void*)g,
        (__attribute__((address_space(3))) void*)l, 16, 0, 0);
}

// row-major staging fallback (fp32/bf16 x input): reg-staged convert
template<int C>
__device__ __forceinline__ void stage(const void* g, size_t off, u16* lds) {
    if constexpr (C == 1) {
        const float* p = (const float*)g + off;
        float4 a = *(const float4*)p;
        float4 b = *(const float4*)(p + 4);
        union { u16 h[8]; short8 v; } pk;
        pk.h[0] = f2h_bits(a.x); pk.h[1] = f2h_bits(a.y);
        pk.h[2] = f2h_bits(a.z); pk.h[3] = f2h_bits(a.w);
        pk.h[4] = f2h_bits(b.x); pk.h[5] = f2h_bits(b.y);
        pk.h[6] = f2h_bits(b.z); pk.h[7] = f2h_bits(b.w);
        *(short8*)lds = pk.v;
    } else {
        uint4 v = *(const uint4*)((const u16*)g + off);
        unsigned int uu[4] = {v.x, v.y, v.z, v.w};
        union { u16 h[8]; short8 v8; } pk;
#pragma unroll
        for (int j = 0; j < 4; ++j) {
            pk.h[2 * j]     = f2h_bits(bf2f(uu[j] & 0xffffu));
            pk.h[2 * j + 1] = f2h_bits(bf2f(uu[j] >> 16));
        }
        *(short8*)lds = pk.v8;
    }
}

// ---------------- conversion kernels (read inputs, write ws tiled) ----------
__global__ __launch_bounds__(256) void conv_w(
    const void* w0, const void* w1, const void* w2,
    const void* b0, const void* b1, const void* b2, u16* wb)
{
    const int z = blockIdx.y;
    const void* w = (z == 0) ? w0 : (z == 1) ? w1 : w2;
    const void* bb = (z == 0) ? b0 : (z == 1) ? b1 : b2;
    const int isbf = detect_bf16(w0);
    const size_t idx = ((size_t)blockIdx.x * 256 + threadIdx.x) * 8;
    const int n = (int)(idx >> 9), kk = (int)(idx & 511);
    float f[8];
    load8(w, idx, isbf, f);
    union { u16 h[8]; uint4 v; } pk;
#pragma unroll
    for (int j = 0; j < 8; ++j) pk.h[j] = f2h_bits(f[j]);
    *(uint4*)(wb + (size_t)z * 262144 + tidx(n, kk, 16)) = pk.v;
    if (blockIdx.x == 0) {
        u16* bbase = wb + 3 * 262144 + z * 512;
#pragma unroll
        for (int j = 0; j < 2; ++j) {
            int i = threadIdx.x * 2 + j;
            bbase[i] = f2h_bits(load1(bb, i, isbf));
        }
    }
}

// x fp32/bf16 -> f16 TILED [RB 128][16 tiles][512 granules] in ws.
__global__ __launch_bounds__(256) void conv_x(
    const void* x, const void* wq_orig, u16* xh)
{
    const int w = threadIdx.x >> 6, l = threadIdx.x & 63;
    const int row = blockIdx.x * 4 + w;
    union { u16 h[8]; uint4 v; } pk;
    if (detect_bf16(wq_orig)) {
        uint4 v = *(const uint4*)((const u16*)x + (size_t)row * 512 + l * 8);
        unsigned int uu[4] = {v.x, v.y, v.z, v.w};
#pragma unroll
        for (int j = 0; j < 4; ++j) {
            pk.h[2 * j]     = f2h_bits(bf2f(uu[j] & 0xffffu));
            pk.h[2 * j + 1] = f2h_bits(bf2f(uu[j] >> 16));
        }
    } else {
        const float* src = (const float*)x + (size_t)row * 512 + l * 8;
        float4 a = *(const float4*)src;
        float4 b = *(const float4*)(src + 4);
        pk.h[0] = f2h_bits(a.x); pk.h[1] = f2h_bits(a.y);
        pk.h[2] = f2h_bits(a.z); pk.h[3] = f2h_bits(a.w);
        pk.h[4] = f2h_bits(b.x); pk.h[5] = f2h_bits(b.y);
        pk.h[6] = f2h_bits(b.z); pk.h[7] = f2h_bits(b.w);
    }
    *(uint4*)(xh + tidx(row, l * 8, 16)) = pk.v;
}

// ---------------- direct-register GEMM core (proj XM=0) ---------------------
template<int ONES>
__device__ __forceinline__ void gemm_direct(
    const u16* __restrict__ A, const u16* __restrict__ B, int nkt,
    float4v acc[4][4], float4v accS[4])
{
    const int t = threadIdx.x;
    const int w = t >> 6, l = t & 63;
    const int lane15 = l & 15, quad = l >> 4;
    const int wm = w & 1, wn = w >> 1;

    short8 ones;
#pragma unroll
    for (int j = 0; j < 8; ++j) ones[j] = (short)0x3C00;   // f16 1.0

    int offA[4], offB[4];
#pragma unroll
    for (int i = 0; i < 4; ++i) {
        const int ra = wm * 64 + i * 16 + lane15;
        offA[i] = (4 * ra + (quad ^ ((ra >> 1) & 3))) * 8;
        const int rb = wn * 64 + i * 16 + lane15;
        offB[i] = (4 * rb + (quad ^ ((rb >> 1) & 3))) * 8;
    }

    for (int kt = 0; kt < nkt; ++kt) {
        const u16* Ak = A + (size_t)kt * 4096;
        const u16* Bk = B + (size_t)kt * 4096;
        short8 af[4], bf[4];
#pragma unroll
        for (int mi = 0; mi < 4; ++mi) af[mi] = *(const short8*)(Ak + offA[mi]);
#pragma unroll
        for (int ni = 0; ni < 4; ++ni) bf[ni] = *(const short8*)(Bk + offB[ni]);
#pragma unroll
        for (int mi = 0; mi < 4; ++mi) {
#pragma unroll
            for (int ni = 0; ni < 4; ++ni)
                acc[mi][ni] = mfma16(af[mi], bf[ni], acc[mi][ni]);
            if (ONES) accS[mi] = mfma16(af[mi], ones, accS[mi]);
        }
    }
}

// ---------------- LDS-staged core (fallback only: fp32/bf16 x) --------------
template<int ONES, int CA, int CB>
__device__ __forceinline__ void gemm_core(
    const void* __restrict__ A, int sA, const void* __restrict__ B, int sB, int K,
    u16* As, u16* Bs, float4v acc[4][4], float4v accS[4])
{
    const int t = threadIdx.x;
    const int w = t >> 6, l = t & 63;
    const int lane15 = l & 15, quad = l >> 4;
    const int wm = w & 1, wn = w >> 1;

    short8 ones;
#pragma unroll
    for (int j = 0; j < 8; ++j) ones[j] = (short)0x3C00;   // f16 1.0

    for (int kt = 0; kt < K; kt += 32) {
        const int kti = kt >> 5;
        __syncthreads();
#pragma unroll
        for (int i = 0; i < 2; ++i) {
            const int fg = w * 128 + i * 64 + l;
            const int r = fg >> 2;
            const int kq = (fg & 3) ^ ((r >> 1) & 3);
            if constexpr (CA == 0)
                gld16((const u16*)A + (size_t)kti * 4096 + fg * 8, As + fg * 8);
            else
                stage<CA>(A, (size_t)r * sA + kt + kq * 8, As + fg * 8);
            if constexpr (CB == 0)
                gld16((const u16*)B + (size_t)kti * 4096 + fg * 8, Bs + fg * 8);
            else
                stage<CB>(B, (size_t)r * sB + kt + kq * 8, Bs + fg * 8);
        }
        __syncthreads();

        short8 af[4], bf[4];
#pragma unroll
        for (int mi = 0; mi < 4; ++mi) {
            const int r = wm * 64 + mi * 16 + lane15;
            af[mi] = *(const short8*)&As[(4 * r + (quad ^ ((r >> 1) & 3))) * 8];
        }
#pragma unroll
        for (int ni = 0; ni < 4; ++ni) {
            const int r = wn * 64 + ni * 16 + lane15;
            bf[ni] = *(const short8*)&Bs[(4 * r + (quad ^ ((r >> 1) & 3))) * 8];
        }
#pragma unroll
        for (int mi = 0; mi < 4; ++mi) {
#pragma unroll
            for (int ni = 0; ni < 4; ++ni)
                acc[mi][ni] = mfma16(af[mi], bf[ni], acc[mi][ni]);
            if (ONES) accS[mi] = mfma16(af[mi], ones, accS[mi]);
        }
    }
}

#define ACC_INIT()                                                     \
    float4v acc[4][4];                                                 \
    float4v accS[4];                                                   \
    _Pragma("unroll") for (int mi = 0; mi < 4; ++mi) {                 \
        accS[mi] = (float4v){0.f, 0.f, 0.f, 0.f};                      \
        _Pragma("unroll") for (int ni = 0; ni < 4; ++ni)               \
            acc[mi][ni] = (float4v){0.f, 0.f, 0.f, 0.f};               \
    }

// ---------------- proj: Q, K, Vt (outputs tiled) ----------------
// XM: 0 = xh tiled f16 (direct core), 1 = x fp32, 2 = x bf16 (LDS fallback).
template<int XM>
__global__ __launch_bounds__(256) void proj_gemm(
    const void* __restrict__ xsrc, const u16* __restrict__ wb,
    u16* __restrict__ qb, u16* __restrict__ kb, u16* __restrict__ vt)
{
    const int t = threadIdx.x;
    const int w = t >> 6, l = t & 63;
    const int lane15 = l & 15, quad = l >> 4;
    const int wm = w & 1, wn = w >> 1;
    (void)l; (void)w;
    ACC_INIT();
    const int z = blockIdx.z;
    // T1 XCD swizzle within the 512-plane (nwg %8==0, bijective)
    const int hh = blockIdx.y * 4 + blockIdx.x;
    const int sl = (hh & 7) * 64 + (hh >> 3);
    const int ty = sl >> 2, tx = sl & 3;
    const u16* bias = wb + 3 * 262144 + z * 512;

    int m0, n0;
    if (z < 2) { m0 = ty * 128; n0 = tx * 128; }
    else       { m0 = tx * 128; n0 = ty * 128; }

    if constexpr (XM == 0) {
        const u16* xt = (const u16*)xsrc;
        if (z < 2) {
            const u16* A = xt + (size_t)(m0 >> 7) * 16 * 4096;
            const u16* B = wb + (size_t)z * 262144 + (size_t)(n0 >> 7) * 16 * 4096;
            gemm_direct<0>(A, B, 16, acc, accS);
        } else {
            const u16* A = wb + (size_t)2 * 262144 + (size_t)(m0 >> 7) * 16 * 4096;
            const u16* B = xt + (size_t)(n0 >> 7) * 16 * 4096;
            gemm_direct<0>(A, B, 16, acc, accS);
        }
    } else {
        __shared__ u16 As[4096] __attribute__((aligned(16)));
        __shared__ u16 Bs[4096] __attribute__((aligned(16)));
        if (z < 2) {
            const void* B = wb + (size_t)z * 262144 + (size_t)(n0 >> 7) * 16 * 4096;
            if (XM == 1) {
                const void* A = (const float*)xsrc + (size_t)m0 * 512;
                gemm_core<0, 1, 0>(A, 512, B, 512, 512, As, Bs, acc, accS);
            } else {
                const void* A = (const u16*)xsrc + (size_t)m0 * 512;
                gemm_core<0, 2, 0>(A, 512, B, 512, 512, As, Bs, acc, accS);
            }
        } else {
            const void* A = wb + (size_t)2 * 262144 + (size_t)(m0 >> 7) * 16 * 4096;
            if (XM == 1) {
                const void* B = (const float*)xsrc + (size_t)n0 * 512;
                gemm_core<0, 0, 1>(A, 512, B, 512, 512, As, Bs, acc, accS);
            } else {
                const void* B = (const u16*)xsrc + (size_t)n0 * 512;
                gemm_core<0, 0, 2>(A, 512, B, 512, 512, As, Bs, acc, accS);
            }
        }
    }

    if (z < 2) {
        u16* dst = z ? kb : qb;                 // tiled [rows/128][16][512]g
        float bcol[4];
#pragma unroll
        for (int ni = 0; ni < 4; ++ni)
            bcol[ni] = h2f(bias[n0 + wn * 64 + ni * 16 + lane15]);
#pragma unroll
        for (int mi = 0; mi < 4; ++mi)
#pragma unroll
            for (int ni = 0; ni < 4; ++ni)
#pragma unroll
                for (int r = 0; r < 4; ++r) {
                    const int row = m0 + wm * 64 + mi * 16 + quad * 4 + r;
                    const int col = n0 + wn * 64 + ni * 16 + lane15;
                    dst[tidx(row, col, 16)] = f2h_bits(acc[mi][ni][r] + bcol[ni]);
                }
    } else {
        // Vt tiled per batch: [b][4 RBe][64 T][512]g ; rows = e, K = token
#pragma unroll
        for (int mi = 0; mi < 4; ++mi)
#pragma unroll
            for (int r = 0; r < 4; ++r) {
                const int e = m0 + wm * 64 + mi * 16 + quad * 4 + r;      // 0..511
                const float bias_e = h2f(bias[e]);
#pragma unroll
                for (int ni = 0; ni < 4; ++ni) {
                    const int tok = n0 + wn * 64 + ni * 16 + lane15;
                    const int b = tok >> 11, kk = tok & 2047;
                    vt[(size_t)b * 1048576 + tidx(e, kk, 64)] =
                        f2h_bits(acc[mi][ni][r] + bias_e);
                }
            }
    }
}

// ---------------- attn: fused S+O, flash-style, 2 blocks/CU -----------------
// Block = 32 q-rows (2 waves x 16q), 128 threads. Grid 512 = 2 blocks/CU.
// b = bid&7 (XCD-pinned), qblk = bid>>3 (0..63).
// Per kv-tile (32): stage K[32][512] + V^T[512][32] (68KB LDS, tiled gld16),
// QK^T 32 MFMA -> mask(reg-prefetched)+exp -> Ps per-wave LDS transpose ->
// rowsum-MFMA + PV 32 MFMA, setprio(1) around MFMA cluster (T5).
__global__ __launch_bounds__(128) void attn(
    const u16* __restrict__ qb, const u16* __restrict__ kb,
    const u16* __restrict__ vtb, const int* __restrict__ mask,
    float* __restrict__ outp)
{
    __shared__ u16 Ks[16384] __attribute__((aligned(16)));   // [kk 16][128 g]
    __shared__ u16 Vs[16384] __attribute__((aligned(16)));   // [erb 4][512 g]
    __shared__ u16 Ps[2][640];                               // [wave][16 x 40]
    const int t = threadIdx.x, w = t >> 6, l = t & 63;
    const int lane15 = l & 15, quad = l >> 4;
    const int bid = blockIdx.x;
    const int b = bid & 7, qblk = bid >> 3;
    const int q0 = qblk * 32 + w * 16;          // wave's first q row (in batch)

    short8 ones;
#pragma unroll
    for (int j = 0; j < 8; ++j) ones[j] = (short)0x3C00;

    // Q fragments: registers, loaded once from tiled qb
    const u16* qtile = qb + (size_t)(b * 16 + (q0 >> 7)) * 16 * 4096;
    const int rq = (q0 & 127) + lane15;
    const int gq = 4 * rq + (quad ^ ((rq >> 1) & 3));
    short8 qf[16];
#pragma unroll
    for (int kk = 0; kk < 16; ++kk)
        qf[kk] = *(const short8*)(qtile + (size_t)kk * 4096 + gq * 8);

    float4v acc[32];
#pragma unroll
    for (int ni = 0; ni < 32; ++ni) acc[ni] = (float4v){0.f, 0.f, 0.f, 0.f};
    float4v accS = (float4v){0.f, 0.f, 0.f, 0.f};

    // mask rows for this lane's 4 q-rows; prefetch tile 0
    const int* mbase = mask + ((size_t)b * 2048 + q0 + quad * 4) * 2048;
    int mk[8];
#pragma unroll
    for (int s = 0; s < 2; ++s)
#pragma unroll
        for (int r = 0; r < 4; ++r)
            mk[s * 4 + r] = mbase[(size_t)r * 2048 + s * 16 + lane15];

    const u16* vbb = vtb + (size_t)b * 1048576;

    for (int kt = 0; kt < 64; ++kt) {
        const int kv0 = kt * 32;
        __syncthreads();                          // LDS free from prev compute
        {   // stage K rows [kv0, kv0+32) x all e  (2048 granules, 16/thread)
            const u16* kbb = kb + (size_t)(b * 16 + (kv0 >> 7)) * 16 * 4096
                                + (size_t)(kv0 & 127) * 32;
#pragma unroll
            for (int i = 0; i < 16; ++i) {
                const int gi = i * 128 + t;
                const int kk = gi >> 7, gl = gi & 127;
                gld16(kbb + (size_t)kk * 4096 + gl * 8, Ks + gi * 8);
            }
            // stage V^T cols [kv0, kv0+32) x all e (2048 granules, 16/thread)
            const u16* vb0 = vbb + (size_t)(kv0 >> 5) * 4096;
#pragma unroll
            for (int i = 0; i < 16; ++i) {
                const int gi = i * 128 + t;
                const int erb = gi >> 9, g = gi & 511;
                gld16(vb0 + (size_t)erb * 64 * 4096 + g * 8, Vs + gi * 8);
            }
        }
        __syncthreads();                          // drain: K/V ready

        // prefetch next tile's mask (completes under the MFMAs below)
        int mkn[8];
        if (kt < 63) {
#pragma unroll
            for (int s = 0; s < 2; ++s)
#pragma unroll
                for (int r = 0; r < 4; ++r)
                    mkn[s * 4 + r] =
                        mbase[(size_t)r * 2048 + kv0 + 32 + s * 16 + lane15];
        }

        // QK^T: 2 kv-sub C-tiles, 32 MFMA
        __builtin_amdgcn_s_setprio(1);
        float4v s0 = (float4v){0.f, 0.f, 0.f, 0.f};
        float4v s1 = (float4v){0.f, 0.f, 0.f, 0.f};
        const int r0 = lane15, r1 = 16 + lane15;
        const int g0 = (4 * r0 + (quad ^ ((r0 >> 1) & 3))) * 8;
        const int g1 = (4 * r1 + (quad ^ ((r1 >> 1) & 3))) * 8;
#pragma unroll
        for (int kk = 0; kk < 16; ++kk) {
            short8 kf0 = *(const short8*)&Ks[kk * 1024 + g0];
            short8 kf1 = *(const short8*)&Ks[kk * 1024 + g1];
            s0 = mfma16(qf[kk], kf0, s0);
            s1 = mfma16(qf[kk], kf1, s1);
        }
        __builtin_amdgcn_s_setprio(0);

        // mask + exp -> Ps (C layout: row q = quad*4+r, col kv = s*16+lane15)
        u16* psw = &Ps[w][0];
#pragma unroll
        for (int r = 0; r < 4; ++r) {
            const float p0 = (mk[r] > 0)     ? 0.f : __expf(s0[r] * SCALE);
            const float p1 = (mk[4 + r] > 0) ? 0.f : __expf(s1[r] * SCALE);
            psw[(quad * 4 + r) * 40 + lane15]      = f2h_bits(p0);
            psw[(quad * 4 + r) * 40 + 16 + lane15] = f2h_bits(p1);
        }
        // A-fragment read: lane holds P[q=lane15][kv=quad*8..+8]
        short8 pa = *(const short8*)&psw[lane15 * 40 + quad * 8];

        __builtin_amdgcn_s_setprio(1);
        accS = mfma16(pa, ones, accS);            // rowsum
#pragma unroll
        for (int ni = 0; ni < 32; ++ni) {         // PV: 32 MFMA
            const int re = (ni * 16 + lane15) & 127;
            short8 vf = *(const short8*)&Vs[(ni >> 3) * 4096 +
                                            (4 * re + (quad ^ ((re >> 1) & 3))) * 8];
            acc[ni] = mfma16(pa, vf, acc[ni]);
        }
        __builtin_amdgcn_s_setprio(0);

        if (kt < 63) {
#pragma unroll
            for (int j = 0; j < 8; ++j) mk[j] = mkn[j];
        }
    }

    // epilogue: out = acc / rowsum
    float* ob = outp + ((size_t)b * 2048 + q0 + quad * 4) * 512;
#pragma unroll
    for (int r = 0; r < 4; ++r) {
        const float inv = 1.f / accS[r];
#pragma unroll
        for (int ni = 0; ni < 32; ++ni)
            ob[(size_t)r * 512 + ni * 16 + lane15] = acc[ni][r] * inv;
    }
}

extern "C" void kernel_launch(void* const* d_in, const int* in_sizes, int n_in,
                              void* d_out, int out_size, void* d_ws, size_t ws_size,
                              hipStream_t stream) {
    const void* x    = d_in[0];
    const int*  mask = (const int*)d_in[1];
    const void* wq   = d_in[2];
    const void* bq   = d_in[3];
    const void* wk   = d_in[4];
    const void* bk   = d_in[5];
    const void* wv   = d_in[6];
    const void* bv   = d_in[7];

    const size_t MB  = 1ull << 20;
    const size_t QSZ = (size_t)NROWS * E_DIM;           // u16 elems per Q/K/Vt/xh

    u16* wb   = (u16*)d_ws;                             // 2 MB (weights+bias f16)
    u16* qb   = (u16*)((char*)d_ws + 2 * MB);
    u16* kb   = qb + QSZ;
    u16* vtb  = kb + QSZ;
    u16* xh   = vtb + QSZ;                              // 16.8 MB f16 x

    const size_t fixed = 2 * MB + 3 * QSZ * 2;          // 52.4 MB (pre-xh)
    const size_t avail = (ws_size > fixed) ? (ws_size - fixed) : 0;
    const int use_xh = avail >= QSZ * 2;

    conv_w<<<dim3(128, 3), 256, 0, stream>>>(wq, wk, wv, bq, bk, bv, wb);

    if (use_xh) {
        conv_x<<<NROWS / 4, 256, 0, stream>>>(x, wq, xh);
        proj_gemm<0><<<dim3(4, 128, 3), 256, 0, stream>>>(xh, wb, qb, kb, vtb);
    } else {
        // small-ws fallback: on-the-fly x conversion; dtype via in_sizes
        // (x fp32 = NROWS*512*4 bytes; 16-bit input = half that).
        if (in_sizes[0] >= (int)(NROWS * 512 * 4))
            proj_gemm<1><<<dim3(4, 128, 3), 256, 0, stream>>>(x, wb, qb, kb, vtb);
        else
            proj_gemm<2><<<dim3(4, 128, 3), 256, 0, stream>>>(x, wb, qb, kb, vtb);
    }

    attn<<<512, 128, 0, stream>>>(qb, kb, vtb, mask, (float*)d_out);
}

// Round 15
// 200.656 us; speedup vs baseline: 1.4441x; 1.4441x over previous
//
#include <hip/hip_runtime.h>
#include <hip/hip_bf16.h>
#include <hip/hip_fp16.h>

// MHAHead B=8,S=2048,E=512. R19: R15 + gemmS -> 256^2 counted-vmcnt pipeline.
//   R11-R15 (2ph drain0) and R14 (256^2 drain0) and R16 (no-LDS) and R17/R18
//   (fused attn, 4 waves/CU) all null/regress. Catalog m218/m230: the lever is
//   COUNTED vmcnt -- prefetch loads stay in flight across a RAW s_barrier;
//   drain-to-0 was the invariant in every null.
//   gemmS256: 512 thr / 8 waves (2Mx4N), tile 256x256, BK=32 double-buffered.
//   Per tile: issue next tile's 4 gld16 -> s_waitcnt vmcnt(4) (current tile
//   only) -> raw s_barrier -> 12 ds_read + 32 MFMA (setprio) -> raw s_barrier.
//   vmcnt(0) only at last tile. LDS 72KB -> 2 blocks/CU.
//   All else (conv_w/conv_x/proj/gemmO/launcher) = R15 verbatim (197.4us best).

typedef unsigned short u16;
typedef unsigned long long u64;
typedef __attribute__((ext_vector_type(8))) short short8;
typedef __attribute__((ext_vector_type(8))) _Float16 half8;
typedef __attribute__((ext_vector_type(4))) float float4v;

#define S_DIM 2048
#define E_DIM 512
#define NROWS (8 * S_DIM)
#define SCALE 0.044194173824159216f

__device__ __forceinline__ float4v mfma16(short8 a, short8 b, float4v c) {
    return __builtin_amdgcn_mfma_f32_16x16x32_f16(
        __builtin_bit_cast(half8, a), __builtin_bit_cast(half8, b), c, 0, 0, 0);
}
__device__ __forceinline__ float bf2f(unsigned int u) {
    union { unsigned int i; float f; } v; v.i = u << 16; return v.f;
}
__device__ __forceinline__ u16 f2h_bits(float f) {
    union { _Float16 h; u16 u; } v; v.h = (_Float16)f; return v.u;
}
__device__ __forceinline__ float h2f(u16 u) {
    union { u16 u; _Float16 h; } v; v.u = u; return (float)v.h;
}
// tiled u16 index for element (row, col) in a [rows][K] matrix with NT=K/32 tiles
__device__ __forceinline__ size_t tidx(int row, int col, int NT) {
    const int rr = row & 127;
    const int g = 4 * rr + (((col & 31) >> 3) ^ ((rr >> 1) & 3));
    return ((size_t)((row >> 7) * NT + (col >> 5)) * 512 + g) * 8 + (col & 7);
}
__device__ __forceinline__ int detect_bf16(const void* wp) {
    const u16* w = (const u16*)wp;
    int cnt = 0;
    for (int i = 0; i < 64; ++i) {
        int e = (w[2 * i] >> 7) & 0xff;
        cnt += (e >= 100 && e <= 131) ? 1 : 0;
    }
    return cnt >= 40;
}
__device__ __forceinline__ void load8(const void* base, size_t idx, int isbf, float* f) {
    if (isbf) {
        uint4 v = *(const uint4*)((const u16*)base + idx);
        f[0] = bf2f(v.x & 0xffffu); f[1] = bf2f(v.x >> 16);
        f[2] = bf2f(v.y & 0xffffu); f[3] = bf2f(v.y >> 16);
        f[4] = bf2f(v.z & 0xffffu); f[5] = bf2f(v.z >> 16);
        f[6] = bf2f(v.w & 0xffffu); f[7] = bf2f(v.w >> 16);
    } else {
        const float* p = (const float*)base + idx;
        float4 a = *(const float4*)p;
        float4 b = *(const float4*)(p + 4);
        f[0] = a.x; f[1] = a.y; f[2] = a.z; f[3] = a.w;
        f[4] = b.x; f[5] = b.y; f[6] = b.z; f[7] = b.w;
    }
}
__device__ __forceinline__ float load1(const void* base, size_t idx, int isbf) {
    return isbf ? bf2f(((const u16*)base)[idx]) : ((const float*)base)[idx];
}

// async 16B global -> LDS (per-lane src, wave-uniform LDS base + lane*16)
__device__ __forceinline__ void gld16(const u16* g, u16* l) {
    __builtin_amdgcn_global_load_lds(
        (const __attribute__((address_space(1))) void*)g,
        (__attribute__((address_space(3))) void*)l, 16, 0, 0);
}

// row-major staging fallback (fp32/bf16 x input): reg-staged convert
template<int C>
__device__ __forceinline__ void stage(const void* g, size_t off, u16* lds) {
    if constexpr (C == 1) {
        const float* p = (const float*)g + off;
        float4 a = *(const float4*)p;
        float4 b = *(const float4*)(p + 4);
        union { u16 h[8]; short8 v; } pk;
        pk.h[0] = f2h_bits(a.x); pk.h[1] = f2h_bits(a.y);
        pk.h[2] = f2h_bits(a.z); pk.h[3] = f2h_bits(a.w);
        pk.h[4] = f2h_bits(b.x); pk.h[5] = f2h_bits(b.y);
        pk.h[6] = f2h_bits(b.z); pk.h[7] = f2h_bits(b.w);
        *(short8*)lds = pk.v;
    } else {
        uint4 v = *(const uint4*)((const u16*)g + off);
        unsigned int uu[4] = {v.x, v.y, v.z, v.w};
        union { u16 h[8]; short8 v8; } pk;
#pragma unroll
        for (int j = 0; j < 4; ++j) {
            pk.h[2 * j]     = f2h_bits(bf2f(uu[j] & 0xffffu));
            pk.h[2 * j + 1] = f2h_bits(bf2f(uu[j] >> 16));
        }
        *(short8*)lds = pk.v8;
    }
}

// ---------------- conversion kernels (read inputs, write ws tiled) ----------
__global__ __launch_bounds__(256) void conv_w(
    const void* w0, const void* w1, const void* w2,
    const void* b0, const void* b1, const void* b2, u16* wb)
{
    const int z = blockIdx.y;
    const void* w = (z == 0) ? w0 : (z == 1) ? w1 : w2;
    const void* bb = (z == 0) ? b0 : (z == 1) ? b1 : b2;
    const int isbf = detect_bf16(w0);
    const size_t idx = ((size_t)blockIdx.x * 256 + threadIdx.x) * 8;
    const int n = (int)(idx >> 9), kk = (int)(idx & 511);
    float f[8];
    load8(w, idx, isbf, f);
    union { u16 h[8]; uint4 v; } pk;
#pragma unroll
    for (int j = 0; j < 8; ++j) pk.h[j] = f2h_bits(f[j]);
    *(uint4*)(wb + (size_t)z * 262144 + tidx(n, kk, 16)) = pk.v;
    if (blockIdx.x == 0) {
        u16* bbase = wb + 3 * 262144 + z * 512;
#pragma unroll
        for (int j = 0; j < 2; ++j) {
            int i = threadIdx.x * 2 + j;
            bbase[i] = f2h_bits(load1(bb, i, isbf));
        }
    }
}

// x fp32/bf16 -> f16 TILED [RB 128][16 tiles][512 granules] in ws.
__global__ __launch_bounds__(256) void conv_x(
    const void* x, const void* wq_orig, u16* xh)
{
    const int w = threadIdx.x >> 6, l = threadIdx.x & 63;
    const int row = blockIdx.x * 4 + w;
    union { u16 h[8]; uint4 v; } pk;
    if (detect_bf16(wq_orig)) {
        uint4 v = *(const uint4*)((const u16*)x + (size_t)row * 512 + l * 8);
        unsigned int uu[4] = {v.x, v.y, v.z, v.w};
#pragma unroll
        for (int j = 0; j < 4; ++j) {
            pk.h[2 * j]     = f2h_bits(bf2f(uu[j] & 0xffffu));
            pk.h[2 * j + 1] = f2h_bits(bf2f(uu[j] >> 16));
        }
    } else {
        const float* src = (const float*)x + (size_t)row * 512 + l * 8;
        float4 a = *(const float4*)src;
        float4 b = *(const float4*)(src + 4);
        pk.h[0] = f2h_bits(a.x); pk.h[1] = f2h_bits(a.y);
        pk.h[2] = f2h_bits(a.z); pk.h[3] = f2h_bits(a.w);
        pk.h[4] = f2h_bits(b.x); pk.h[5] = f2h_bits(b.y);
        pk.h[6] = f2h_bits(b.z); pk.h[7] = f2h_bits(b.w);
    }
    *(uint4*)(xh + tidx(row, l * 8, 16)) = pk.v;
}

// ---------------- LDS-staged GEMM core (R15: BK=32, 4 waves, tiled gld16) ---
template<int ONES, int CA, int CB>
__device__ __forceinline__ void gemm_core(
    const void* __restrict__ A, int sA, const void* __restrict__ B, int sB, int K,
    u16* As, u16* Bs, float4v acc[4][4], float4v accS[4])
{
    const int t = threadIdx.x;
    const int w = t >> 6, l = t & 63;
    const int lane15 = l & 15, quad = l >> 4;
    const int wm = w & 1, wn = w >> 1;

    short8 ones;
#pragma unroll
    for (int j = 0; j < 8; ++j) ones[j] = (short)0x3C00;   // f16 1.0

    for (int kt = 0; kt < K; kt += 32) {
        const int kti = kt >> 5;
        __syncthreads();
#pragma unroll
        for (int i = 0; i < 2; ++i) {
            const int fg = w * 128 + i * 64 + l;
            const int r = fg >> 2;
            const int kq = (fg & 3) ^ ((r >> 1) & 3);
            if constexpr (CA == 0)
                gld16((const u16*)A + (size_t)kti * 4096 + fg * 8, As + fg * 8);
            else
                stage<CA>(A, (size_t)r * sA + kt + kq * 8, As + fg * 8);
            if constexpr (CB == 0)
                gld16((const u16*)B + (size_t)kti * 4096 + fg * 8, Bs + fg * 8);
            else
                stage<CB>(B, (size_t)r * sB + kt + kq * 8, Bs + fg * 8);
        }
        __syncthreads();

        short8 af[4], bf[4];
#pragma unroll
        for (int mi = 0; mi < 4; ++mi) {
            const int r = wm * 64 + mi * 16 + lane15;
            af[mi] = *(const short8*)&As[(4 * r + (quad ^ ((r >> 1) & 3))) * 8];
        }
#pragma unroll
        for (int ni = 0; ni < 4; ++ni) {
            const int r = wn * 64 + ni * 16 + lane15;
            bf[ni] = *(const short8*)&Bs[(4 * r + (quad ^ ((r >> 1) & 3))) * 8];
        }
#pragma unroll
        for (int mi = 0; mi < 4; ++mi) {
#pragma unroll
            for (int ni = 0; ni < 4; ++ni)
                acc[mi][ni] = mfma16(af[mi], bf[ni], acc[mi][ni]);
            if (ONES) accS[mi] = mfma16(af[mi], ones, accS[mi]);
        }
    }
}

#define GEMM_PRE()                                                     \
    __shared__ u16 As[4096] __attribute__((aligned(16)));              \
    __shared__ u16 Bs[4096] __attribute__((aligned(16)));              \
    const int t = threadIdx.x;                                         \
    const int w = t >> 6, l = t & 63;                                  \
    const int lane15 = l & 15, quad = l >> 4;                          \
    const int wm = w & 1, wn = w >> 1;                                 \
    (void)l; (void)w;                                                  \
    float4v acc[4][4];                                                 \
    float4v accS[4];                                                   \
    _Pragma("unroll") for (int mi = 0; mi < 4; ++mi) {                 \
        accS[mi] = (float4v){0.f, 0.f, 0.f, 0.f};                      \
        _Pragma("unroll") for (int ni = 0; ni < 4; ++ni)               \
            acc[mi][ni] = (float4v){0.f, 0.f, 0.f, 0.f};               \
    }

// ---------------- proj: Q, K, Vt (outputs tiled; R15 verbatim) --------------
template<int XM>
__global__ __launch_bounds__(256) void proj_gemm(
    const void* __restrict__ xsrc, const u16* __restrict__ wb,
    u16* __restrict__ qb, u16* __restrict__ kb, u16* __restrict__ vt)
{
    GEMM_PRE();
    const int z = blockIdx.z;
    const int hh = blockIdx.y * 4 + blockIdx.x;
    const int sl = (hh & 7) * 64 + (hh >> 3);
    const int ty = sl >> 2, tx = sl & 3;
    const u16* bias = wb + 3 * 262144 + z * 512;

    int m0, n0;
    if (z < 2) { m0 = ty * 128; n0 = tx * 128; }
    else       { m0 = tx * 128; n0 = ty * 128; }

    if (z < 2) {
        const void* B = wb + (size_t)z * 262144 + (size_t)(n0 >> 7) * 16 * 4096;
        if (XM == 0) {
            const void* A = (const u16*)xsrc + (size_t)(m0 >> 7) * 16 * 4096;
            gemm_core<0, 0, 0>(A, 512, B, 512, 512, As, Bs, acc, accS);
        } else if (XM == 1) {
            const void* A = (const float*)xsrc + (size_t)m0 * 512;
            gemm_core<0, 1, 0>(A, 512, B, 512, 512, As, Bs, acc, accS);
        } else {
            const void* A = (const u16*)xsrc + (size_t)m0 * 512;
            gemm_core<0, 2, 0>(A, 512, B, 512, 512, As, Bs, acc, accS);
        }
    } else {
        const void* A = wb + (size_t)2 * 262144 + (size_t)(m0 >> 7) * 16 * 4096;
        if (XM == 0) {
            const void* B = (const u16*)xsrc + (size_t)(n0 >> 7) * 16 * 4096;
            gemm_core<0, 0, 0>(A, 512, B, 512, 512, As, Bs, acc, accS);
        } else if (XM == 1) {
            const void* B = (const float*)xsrc + (size_t)n0 * 512;
            gemm_core<0, 0, 1>(A, 512, B, 512, 512, As, Bs, acc, accS);
        } else {
            const void* B = (const u16*)xsrc + (size_t)n0 * 512;
            gemm_core<0, 0, 2>(A, 512, B, 512, 512, As, Bs, acc, accS);
        }
    }

    if (z < 2) {
        u16* dst = z ? kb : qb;                 // tiled [rows/128][16][512]g
        float bcol[4];
#pragma unroll
        for (int ni = 0; ni < 4; ++ni)
            bcol[ni] = h2f(bias[n0 + wn * 64 + ni * 16 + lane15]);
#pragma unroll
        for (int mi = 0; mi < 4; ++mi)
#pragma unroll
            for (int ni = 0; ni < 4; ++ni)
#pragma unroll
                for (int r = 0; r < 4; ++r) {
                    const int row = m0 + wm * 64 + mi * 16 + quad * 4 + r;
                    const int col = n0 + wn * 64 + ni * 16 + lane15;
                    dst[tidx(row, col, 16)] = f2h_bits(acc[mi][ni][r] + bcol[ni]);
                }
    } else {
        // Vt tiled per batch: [b][4 RBe][64 T][512]g ; rows = e, K = token
#pragma unroll
        for (int mi = 0; mi < 4; ++mi)
#pragma unroll
            for (int r = 0; r < 4; ++r) {
                const int e = m0 + wm * 64 + mi * 16 + quad * 4 + r;      // 0..511
                const float bias_e = h2f(bias[e]);
#pragma unroll
                for (int ni = 0; ni < 4; ++ni) {
                    const int tok = n0 + wn * 64 + ni * 16 + lane15;
                    const int b = tok >> 11, kk = tok & 2047;
                    vt[(size_t)b * 1048576 + tidx(e, kk, 64)] =
                        f2h_bits(acc[mi][ni][r] + bias_e);
                }
            }
    }
}

// ---------------- gemmS: 256^2, 8 waves, counted-vmcnt double-buffer --------
// Tile 256x256, BK=32 (one stored tile), LDS 2x16KB per operand + 8KB mask.
// Pipeline: prefetch next tile -> s_waitcnt vmcnt(4) -> raw barrier ->
// ds_read+MFMA -> raw barrier. Prefetch stays in flight across barriers (T4).
__global__ __launch_bounds__(512, 2) void gemmS(
    const u16* __restrict__ qb, const u16* __restrict__ kb,
    const int* __restrict__ mask, u16* __restrict__ Sdst, int b0)
{
    __shared__ u16 As[16384] __attribute__((aligned(16)));  // 2 bufs x 1024 g
    __shared__ u16 Bs[16384] __attribute__((aligned(16)));
    __shared__ u64 maskw[1024];                             // [wave][128 rows]
    const int t = threadIdx.x, w = t >> 6, l = t & 63;
    const int lane15 = l & 15, quad = l >> 4;
    const int wm = w & 1, wn = w >> 1;
    const int zb = blockIdx.z, b = b0 + zb;
    // T1 XCD swizzle: plane nwg=64 (8x8 tiles of 256^2)
    const int hh = blockIdx.y * 8 + blockIdx.x;
    const int sl = (hh & 7) * 8 + (hh >> 3);
    const int m0 = (sl >> 3) * 256, n0 = (sl & 7) * 256;

    {   // mask pack: wave covers rows m0+wm*128+[0,128), cols n0+wn*64+l
        const int* mrow = mask + ((size_t)b * S_DIM + m0 + wm * 128) * S_DIM
                               + n0 + wn * 64 + l;
#pragma unroll
        for (int rnd = 0; rnd < 8; ++rnd) {
            int v[16];
#pragma unroll
            for (int i = 0; i < 16; ++i)
                v[i] = mrow[(size_t)(rnd * 16 + i) * S_DIM];
            u64 bb[16];
#pragma unroll
            for (int i = 0; i < 16; ++i)
                bb[i] = __ballot(v[i] > 0);
            if (l == 0) {
#pragma unroll
                for (int i = 0; i < 16; ++i)
                    maskw[w * 128 + rnd * 16 + i] = bb[i];
            }
        }
    }
    asm volatile("s_waitcnt vmcnt(0)" ::: "memory");   // clean slate for pipeline

    const u16* Ab = qb + (size_t)((b * S_DIM + m0) >> 7) * 16 * 4096;
    const u16* Bb = kb + (size_t)((b * S_DIM + n0) >> 7) * 16 * 4096;

    float4v acc[8][4];
#pragma unroll
    for (int mi = 0; mi < 8; ++mi)
#pragma unroll
        for (int ni = 0; ni < 4; ++ni)
            acc[mi][ni] = (float4v){0.f, 0.f, 0.f, 0.f};

    // stage tile kt into buffer buf: 1024 granules/operand, 2/thread (4 gld16)
    auto stageS = [&](int kt, int buf) {
#pragma unroll
        for (int i = 0; i < 2; ++i) {
            const int gi = i * 512 + t;                      // 0..1023
            const size_t src = ((size_t)(gi >> 9) * 16 + kt) * 4096
                             + (size_t)(gi & 511) * 8;
            gld16(Ab + src, As + buf * 8192 + gi * 8);
            gld16(Bb + src, Bs + buf * 8192 + gi * 8);
        }
    };

    stageS(0, 0);
    int cur = 0;
    for (int kt = 0; kt < 16; ++kt) {
        if (kt < 15) {
            stageS(kt + 1, cur ^ 1);                         // 8 in flight
            asm volatile("s_waitcnt vmcnt(4)" ::: "memory"); // current tile done
        } else {
            asm volatile("s_waitcnt vmcnt(0)" ::: "memory"); // epilogue drain
        }
        __builtin_amdgcn_s_barrier();                        // raw: no drain
        __builtin_amdgcn_sched_barrier(0);

        const int bo = cur * 8192;
        short8 bfr[4];
#pragma unroll
        for (int ni = 0; ni < 4; ++ni) {
            const int rn = wn * 64 + ni * 16 + lane15;       // 0..255
            bfr[ni] = *(const short8*)&Bs[bo + (4 * rn + (quad ^ ((rn >> 1) & 3))) * 8];
        }
        __builtin_amdgcn_s_setprio(1);
#pragma unroll
        for (int mh = 0; mh < 2; ++mh) {
            short8 af[4];
#pragma unroll
            for (int q4 = 0; q4 < 4; ++q4) {
                const int ra = wm * 128 + (mh * 4 + q4) * 16 + lane15;
                af[q4] = *(const short8*)&As[bo + (4 * ra + (quad ^ ((ra >> 1) & 3))) * 8];
            }
#pragma unroll
            for (int q4 = 0; q4 < 4; ++q4)
#pragma unroll
                for (int ni = 0; ni < 4; ++ni)
                    acc[mh * 4 + q4][ni] = mfma16(af[q4], bfr[ni], acc[mh * 4 + q4][ni]);
        }
        __builtin_amdgcn_s_setprio(0);
        __builtin_amdgcn_sched_barrier(0);
        __builtin_amdgcn_s_barrier();                        // reads done; buf reusable
        cur ^= 1;
    }

    // epilogue: mask + exp, tiled store (NT=64)
    u16* Sb = Sdst + (size_t)zb * 4194304;
#pragma unroll
    for (int mi = 0; mi < 8; ++mi)
#pragma unroll
        for (int r = 0; r < 4; ++r) {
            const int rl = mi * 16 + quad * 4 + r;           // 0..127 in wave
            const int row = m0 + wm * 128 + rl;
            const u64 wbits = maskw[w * 128 + rl];
            const int col0 = n0 + wn * 64 + lane15;
#pragma unroll
            for (int ni = 0; ni < 4; ++ni) {
                const int masked = (int)((wbits >> (lane15 + ni * 16)) & 1);
                const float p = masked ? 0.f : __expf(acc[mi][ni][r] * SCALE);
                Sb[tidx(row, col0 + ni * 16, 64)] = f2h_bits(p);
            }
        }
}

// ---------------- gemmO: out = (S @ Vt) / rowsum(S), phased (R15 verbatim) --
__global__ __launch_bounds__(256) void gemmO(
    const u16* __restrict__ Ssrc, const u16* __restrict__ vt,
    float* __restrict__ outp, int b0)
{
    GEMM_PRE();
    const int zb = blockIdx.z;
    const int b = b0 + zb;
    const int hh = blockIdx.y * 4 + blockIdx.x;
    const int sl = (hh & 7) * 8 + (hh >> 3);
    const int m0 = (sl >> 2) * 128, n0 = (sl & 3) * 128;
    const u16* A = Ssrc + (size_t)zb * 4194304 + (size_t)(m0 >> 7) * 64 * 4096;
    const u16* B = vt + (size_t)b * 1048576 + (size_t)(n0 >> 7) * 64 * 4096;

    gemm_core<1, 0, 0>(A, S_DIM, B, S_DIM, S_DIM, As, Bs, acc, accS);

#pragma unroll
    for (int mi = 0; mi < 4; ++mi)
#pragma unroll
        for (int r = 0; r < 4; ++r) {
            const int row = m0 + wm * 64 + mi * 16 + quad * 4 + r;
            const float inv = 1.f / accS[mi][r];
#pragma unroll
            for (int ni = 0; ni < 4; ++ni) {
                const int col = n0 + wn * 64 + ni * 16 + lane15;
                outp[((size_t)b * S_DIM + row) * E_DIM + col] = acc[mi][ni][r] * inv;
            }
        }
}

extern "C" void kernel_launch(void* const* d_in, const int* in_sizes, int n_in,
                              void* d_out, int out_size, void* d_ws, size_t ws_size,
                              hipStream_t stream) {
    const void* x    = d_in[0];
    const int*  mask = (const int*)d_in[1];
    const void* wq   = d_in[2];
    const void* bq   = d_in[3];
    const void* wk   = d_in[4];
    const void* bk   = d_in[5];
    const void* wv   = d_in[6];
    const void* bv   = d_in[7];

    const size_t MB   = 1ull << 20;
    const size_t QSZ  = (size_t)NROWS * E_DIM;          // u16 elems per Q/K/Vt/xh
    const size_t S_PB = (size_t)S_DIM * S_DIM;          // u16 elems per S batch

    u16* wb   = (u16*)d_ws;                             // 2 MB (weights+bias f16)
    u16* qb   = (u16*)((char*)d_ws + 2 * MB);
    u16* kb   = qb + QSZ;
    u16* vtb  = kb + QSZ;
    u16* xh   = vtb + QSZ;                              // 16.8 MB f16 x (dead after proj)
    u16* sS   = xh;                                     // S scratch aliases xh

    const size_t fixed = 2 * MB + 3 * QSZ * 2;          // 52.4 MB (pre-xh)
    const size_t avail = (ws_size > fixed) ? (ws_size - fixed) : 0;
    const int use_xh = avail >= (QSZ * 2 + 2 * S_PB);   // xh + >=2 S batches
    const size_t availB = avail / (S_PB * 2);
    const int P = (availB >= 8) ? 8 : (availB >= 4) ? 4 : (availB >= 2) ? 2 : 1;

    conv_w<<<dim3(128, 3), 256, 0, stream>>>(wq, wk, wv, bq, bk, bv, wb);

    if (use_xh) {
        conv_x<<<NROWS / 4, 256, 0, stream>>>(x, wq, xh);
        proj_gemm<0><<<dim3(4, 128, 3), 256, 0, stream>>>(xh, wb, qb, kb, vtb);
    } else {
        // small-ws fallback: on-the-fly x conversion; dtype via in_sizes
        // (x fp32 = NROWS*512*4 bytes; 16-bit input = half that).
        if (in_sizes[0] >= (int)(NROWS * 512 * 4))
            proj_gemm<1><<<dim3(4, 128, 3), 256, 0, stream>>>(x, wb, qb, kb, vtb);
        else
            proj_gemm<2><<<dim3(4, 128, 3), 256, 0, stream>>>(x, wb, qb, kb, vtb);
    }

    for (int p = 0; p < 8; p += P) {
        gemmS<<<dim3(8, 8, P), 512, 0, stream>>>(qb, kb, mask, sS, p);
        gemmO<<<dim3(4, 16, P), 256, 0, stream>>>(sS, vtb, (float*)d_out, p);
    }
}